// Round 3
// baseline (93.093 us; speedup 1.0000x reference)
//
#include <hip/hip_runtime.h>
#include <hip/hip_bf16.h>

#define BATCHN 16
#define SEQ 4096
#define HIDDEN 128
#define STATE 256
#define MTOT (BATCHN*SEQ)    // 65536
#define NCHUNK 64
#define LCHUNK 64            // SEQ / NCHUNK

typedef __bf16 bf16;
typedef __bf16 bf16x4 __attribute__((ext_vector_type(4)));
typedef __bf16 bf16x8 __attribute__((ext_vector_type(8)));
typedef float f32x4 __attribute__((ext_vector_type(4)));

// per-state scan params computed locally (deterministic fp32, same every block)
__device__ __forceinline__ void scan_params(const float* __restrict__ A_diag,
        const float* __restrict__ steps, int n,
        float& m11, float& m12, float& m21, float& m22, float& c1, float& c2) {
    float st = 1.0f / (1.0f + expf(-steps[n]));
    float A  = fmaxf(A_diag[n], 0.0f);
    float s2A = st * st * A;
    float schur = 1.0f / (1.0f + s2A);
    m11 = 1.0f - s2A * schur;
    m12 = -st * A * schur;
    m21 = st * schur;
    m22 = schur;
    c1 = m11 * st;
    c2 = m21 * st;
}

// load 8 consecutive fp32 -> bf16x8 fragment
__device__ __forceinline__ bf16x8 load_frag_f32(const float* __restrict__ src) {
    float4 a = *reinterpret_cast<const float4*>(src);
    float4 b = *reinterpret_cast<const float4*>(src + 4);
    bf16x8 r = { (bf16)a.x, (bf16)a.y, (bf16)a.z, (bf16)a.w,
                 (bf16)b.x, (bf16)b.y, (bf16)b.z, (bf16)b.w };
    return r;
}

// stage x tile (fp32->bf16) into xl
__device__ __forceinline__ void stage_x(const float* __restrict__ x, int m0, int tid,
                                        bf16 (*xl)[136]) {
    #pragma unroll
    for (int p = 0; p < 8; ++p) {
        int flat = p * 256 + tid;          // 64 rows x 32 float4
        int row = flat >> 5;
        int c4  = flat & 31;
        float4 v = *reinterpret_cast<const float4*>(&x[(size_t)(m0 + row) * HIDDEN + c4 * 4]);
        bf16x4 w = { (bf16)v.x, (bf16)v.y, (bf16)v.z, (bf16)v.w };
        *reinterpret_cast<bf16x4*>(&xl[row][c4 * 4]) = w;
    }
}

// GEMM1 with preloaded B fragments; writes Bu tile to bu LDS
__device__ __forceinline__ void gemm1_to_lds(const bf16 (*xl)[136],
        const bf16x8 breg[4][4], int lane, int n0, bf16 (*bu)[264]) {
    const int lr = lane & 15;
    const int lk = (lane >> 4) * 8;
    f32x4 acc[4][4];
    #pragma unroll
    for (int i = 0; i < 4; ++i)
        #pragma unroll
        for (int j = 0; j < 4; ++j) acc[i][j] = f32x4{0.f, 0.f, 0.f, 0.f};
    #pragma unroll
    for (int ks = 0; ks < 4; ++ks) {
        int k = ks * 32 + lk;
        bf16x8 a[4];
        #pragma unroll
        for (int mf = 0; mf < 4; ++mf)
            a[mf] = *reinterpret_cast<const bf16x8*>(&xl[mf * 16 + lr][k]);
        #pragma unroll
        for (int mf = 0; mf < 4; ++mf)
            #pragma unroll
            for (int nf = 0; nf < 4; ++nf)
                acc[mf][nf] = __builtin_amdgcn_mfma_f32_16x16x32_bf16(a[mf], breg[ks][nf], acc[mf][nf], 0, 0, 0);
    }
    const int mrow = (lane >> 4) * 4;
    #pragma unroll
    for (int mf = 0; mf < 4; ++mf)
        #pragma unroll
        for (int nf = 0; nf < 4; ++nf)
            #pragma unroll
            for (int r = 0; r < 4; ++r)
                bu[mf * 16 + mrow + r][n0 + nf * 16 + lr] = (bf16)acc[mf][nf][r];
}

// ---------------- K1: GEMM1 + local chunk scan (phase A) -> cs ----------------
__global__ __launch_bounds__(256, 3) void k1_gemm_scanA(const float* __restrict__ x,
        const float* __restrict__ Bm, const float* __restrict__ A_diag,
        const float* __restrict__ steps, float* __restrict__ cs) {
    __shared__ bf16 xl[64][136];
    __shared__ bf16 bu[64][264];
    const int tid = threadIdx.x;
    const int m0 = blockIdx.x * 64;
    const int wid = tid >> 6, lane = tid & 63;
    const int lr = lane & 15, lk = (lane >> 4) * 8;
    const int n0 = wid * 64;
    // preload B frags (issue before/while x staging waits)
    bf16x8 breg[4][4];
    #pragma unroll
    for (int ks = 0; ks < 4; ++ks)
        #pragma unroll
        for (int nf = 0; nf < 4; ++nf)
            breg[ks][nf] = load_frag_f32(&Bm[(size_t)(n0 + nf * 16 + lr) * HIDDEN + ks * 32 + lk]);
    stage_x(x, m0, tid, xl);
    __syncthreads();
    gemm1_to_lds(xl, breg, lane, n0, bu);
    // local scan params
    const int n = tid;
    float m11, m12, m21, m22, c1, c2;
    scan_params(A_diag, steps, n, m11, m12, m21, m22, c1, c2);
    __syncthreads();
    float s1 = 0.f, s2 = 0.f;
    #pragma unroll 8
    for (int t = 0; t < LCHUNK; ++t) {
        float v = (float)bu[t][n];
        float ns1 = fmaf(m11, s1, fmaf(m12, s2, c1 * v));
        float ns2 = fmaf(m21, s1, fmaf(m22, s2, c2 * v));
        s1 = ns1; s2 = ns2;
    }
    const int b = m0 >> 12;            // /SEQ
    const int chunk = (m0 >> 6) & (NCHUNK - 1);
    size_t base = ((size_t)(b * NCHUNK + chunk) * 2) * STATE + n;
    cs[base] = s1;
    cs[base + STATE] = s2;
}

// ---------------- phase B: cross-chunk combine (M^64 via squaring) ----------------
__global__ __launch_bounds__(256) void scan_comb(float* __restrict__ cs,
        const float* __restrict__ A_diag, const float* __restrict__ steps) {
    const int n = threadIdx.x;
    const int b = blockIdx.x;
    float p11, p12, p21, p22, c1u, c2u;
    scan_params(A_diag, steps, n, p11, p12, p21, p22, c1u, c2u);
    #pragma unroll
    for (int i = 0; i < 6; ++i) {   // M^(2^6) = M^64
        float q11 = p11 * p11 + p12 * p21;
        float q12 = p11 * p12 + p12 * p22;
        float q21 = p21 * p11 + p22 * p21;
        float q22 = p21 * p12 + p22 * p22;
        p11 = q11; p12 = q12; p21 = q21; p22 = q22;
    }
    float S1 = 0.f, S2 = 0.f;
    #pragma unroll 8
    for (int c = 0; c < NCHUNK; ++c) {
        size_t base = ((size_t)(b * NCHUNK + c) * 2) * STATE + n;
        float q1 = cs[base], q2 = cs[base + STATE];
        cs[base] = S1; cs[base + STATE] = S2;
        float n1 = fmaf(p11, S1, fmaf(p12, S2, q1));
        float n2 = fmaf(p21, S1, fmaf(p22, S2, q2));
        S1 = n1; S2 = n2;
    }
}

// ---------------- K2: GEMM1 (recompute) + phase-C scan + GEMM2 + D*x ----------------
__global__ __launch_bounds__(256, 3) void k2_gemm_scan_gemm(const float* __restrict__ x,
        const float* __restrict__ Bm, const float* __restrict__ Cm,
        const float* __restrict__ A_diag, const float* __restrict__ steps,
        const float* __restrict__ cs, const float* __restrict__ Dv,
        float* __restrict__ out) {
    __shared__ bf16 xl[64][136];
    __shared__ bf16 bu[64][264];            // reused as fp32 [64][132] for epilogue
    float (*ldsF)[132] = reinterpret_cast<float(*)[132]>(&bu[0][0]);
    const int tid = threadIdx.x;
    const int m0 = blockIdx.x * 64;
    const int wid = tid >> 6, lane = tid & 63;
    const int lr = lane & 15, lk = (lane >> 4) * 8;
    const int n0 = wid * 64;
    const int h0 = wid * 32;
    // preload B frags
    bf16x8 breg[4][4];
    #pragma unroll
    for (int ks = 0; ks < 4; ++ks)
        #pragma unroll
        for (int nf = 0; nf < 4; ++nf)
            breg[ks][nf] = load_frag_f32(&Bm[(size_t)(n0 + nf * 16 + lr) * HIDDEN + ks * 32 + lk]);
    stage_x(x, m0, tid, xl);
    __syncthreads();
    gemm1_to_lds(xl, breg, lane, n0, bu);
    // preload C frags now -> latency hides under scan
    bf16x8 creg[8][2];
    #pragma unroll
    for (int ks = 0; ks < 8; ++ks)
        #pragma unroll
        for (int hf = 0; hf < 2; ++hf)
            creg[ks][hf] = load_frag_f32(&Cm[(size_t)(h0 + hf * 16 + lr) * STATE + ks * 32 + lk]);
    // scan params + init state
    const int n = tid;
    float m11, m12, m21, m22, c1, c2;
    scan_params(A_diag, steps, n, m11, m12, m21, m22, c1, c2);
    const int b = m0 >> 12;
    const int chunk = (m0 >> 6) & (NCHUNK - 1);
    size_t cbase = ((size_t)(b * NCHUNK + chunk) * 2) * STATE + n;
    float s1 = cs[cbase], s2 = cs[cbase + STATE];
    __syncthreads();
    // phase-C scan; overwrite bu with y = s2 (bf16)
    #pragma unroll 8
    for (int t = 0; t < LCHUNK; ++t) {
        float v = (float)bu[t][n];
        float ns1 = fmaf(m11, s1, fmaf(m12, s2, c1 * v));
        float ns2 = fmaf(m21, s1, fmaf(m22, s2, c2 * v));
        s1 = ns1; s2 = ns2;
        bu[t][n] = (bf16)s2;
    }
    __syncthreads();
    // GEMM2: y @ C^T for this wave's h-slice
    f32x4 acc2[4][2];
    #pragma unroll
    for (int i = 0; i < 4; ++i) {
        acc2[i][0] = f32x4{0.f, 0.f, 0.f, 0.f};
        acc2[i][1] = f32x4{0.f, 0.f, 0.f, 0.f};
    }
    #pragma unroll
    for (int ks = 0; ks < 8; ++ks) {
        int k = ks * 32 + lk;
        bf16x8 a[4];
        #pragma unroll
        for (int mf = 0; mf < 4; ++mf)
            a[mf] = *reinterpret_cast<const bf16x8*>(&bu[mf * 16 + lr][k]);
        #pragma unroll
        for (int mf = 0; mf < 4; ++mf)
            #pragma unroll
            for (int hf = 0; hf < 2; ++hf)
                acc2[mf][hf] = __builtin_amdgcn_mfma_f32_16x16x32_bf16(a[mf], creg[ks][hf], acc2[mf][hf], 0, 0, 0);
    }
    __syncthreads();   // all bu reads done before fp32 reuse
    // stage acc2 -> ldsF[t][h]
    const int mrow = (lane >> 4) * 4;
    #pragma unroll
    for (int mf = 0; mf < 4; ++mf)
        #pragma unroll
        for (int hf = 0; hf < 2; ++hf)
            #pragma unroll
            for (int r = 0; r < 4; ++r)
                ldsF[mf * 16 + mrow + r][h0 + hf * 16 + lr] = acc2[mf][hf][r];
    __syncthreads();
    // coalesced epilogue: out = ldsF + D*x, float4 stores
    #pragma unroll
    for (int p = 0; p < 8; ++p) {
        int flat = p * 256 + tid;
        int row = flat >> 5;
        int c4  = flat & 31;
        float4 f = *reinterpret_cast<const float4*>(&ldsF[row][c4 * 4]);
        bf16x4 xv = *reinterpret_cast<const bf16x4*>(&xl[row][c4 * 4]);
        float4 d = *reinterpret_cast<const float4*>(&Dv[c4 * 4]);
        float4 o;
        o.x = f.x + d.x * (float)xv.x;
        o.y = f.y + d.y * (float)xv.y;
        o.z = f.z + d.z * (float)xv.z;
        o.w = f.w + d.w * (float)xv.w;
        *reinterpret_cast<float4*>(&out[(size_t)(m0 + row) * HIDDEN + c4 * 4]) = o;
    }
}

extern "C" void kernel_launch(void* const* d_in, const int* in_sizes, int n_in,
                              void* d_out, int out_size, void* d_ws, size_t ws_size,
                              hipStream_t stream) {
    const float* x      = (const float*)d_in[0];
    const float* A_diag = (const float*)d_in[1];
    const float* steps  = (const float*)d_in[2];
    const float* Bm     = (const float*)d_in[3];
    const float* Cm     = (const float*)d_in[4];
    const float* Dv     = (const float*)d_in[5];
    float* out = (float*)d_out;

    float* cs = (float*)d_ws;   // BATCHN*NCHUNK*2*STATE fp32 = 2 MB

    hipLaunchKernelGGL(k1_gemm_scanA, dim3(MTOT / 64), dim3(256), 0, stream,
                       x, Bm, A_diag, steps, cs);
    hipLaunchKernelGGL(scan_comb, dim3(BATCHN), dim3(256), 0, stream, cs, A_diag, steps);
    hipLaunchKernelGGL(k2_gemm_scan_gemm, dim3(MTOT / 64), dim3(256), 0, stream,
                       x, Bm, Cm, A_diag, steps, cs, Dv, out);
}

// Round 4
// 58.124 us; speedup vs baseline: 1.6016x; 1.6016x over previous
//
#include <hip/hip_runtime.h>
#include <hip/hip_bf16.h>

#define BATCHN 16
#define SEQ 4096
#define HIDDEN 128
#define STATE 256
#define MTOT (BATCHN*SEQ)    // 65536
#define NCHUNK 64
#define LCHUNK 64            // SEQ / NCHUNK

typedef __bf16 bf16;
typedef __bf16 bf16x4 __attribute__((ext_vector_type(4)));
typedef __bf16 bf16x8 __attribute__((ext_vector_type(8)));
typedef float f32x4 __attribute__((ext_vector_type(4)));

// per-state scan params (deterministic fp32, same everywhere)
__device__ __forceinline__ void scan_params(const float* __restrict__ A_diag,
        const float* __restrict__ steps, int n,
        float& m11, float& m12, float& m21, float& m22, float& c1, float& c2) {
    float st = 1.0f / (1.0f + expf(-steps[n]));
    float A  = fmaxf(A_diag[n], 0.0f);
    float s2A = st * st * A;
    float schur = 1.0f / (1.0f + s2A);
    m11 = 1.0f - s2A * schur;
    m12 = -st * A * schur;
    m21 = st * schur;
    m22 = schur;
    c1 = m11 * st;
    c2 = m21 * st;
}

// ---------------- setup: bf16 copies of B, C ----------------
__global__ __launch_bounds__(256) void setup_k(const float* __restrict__ Bm,
        const float* __restrict__ Cm, bf16* __restrict__ Bbf, bf16* __restrict__ Cbf) {
    int idx = blockIdx.x * 256 + threadIdx.x;   // grid 128 -> 32768
    Bbf[idx] = (bf16)Bm[idx];
    Cbf[idx] = (bf16)Cm[idx];
}

// stage x tile (fp32->bf16) into xl
__device__ __forceinline__ void stage_x(const float* __restrict__ x, int m0, int tid,
                                        bf16 (*xl)[136]) {
    #pragma unroll
    for (int p = 0; p < 8; ++p) {
        int flat = p * 256 + tid;          // 64 rows x 32 float4
        int row = flat >> 5;
        int c4  = flat & 31;
        float4 v = *reinterpret_cast<const float4*>(&x[(size_t)(m0 + row) * HIDDEN + c4 * 4]);
        bf16x4 w = { (bf16)v.x, (bf16)v.y, (bf16)v.z, (bf16)v.w };
        *reinterpret_cast<bf16x4*>(&xl[row][c4 * 4]) = w;
    }
}

// ---------------- K1: GEMM1 + Bu store + local chunk scan (phase A) ----------------
__global__ __launch_bounds__(256, 3) void k1_gemm_scanA(const float* __restrict__ x,
        const bf16* __restrict__ Bbf, const float* __restrict__ A_diag,
        const float* __restrict__ steps, float* __restrict__ cs,
        bf16* __restrict__ Bu_g) {
    __shared__ bf16 xl[64][136];
    __shared__ bf16 bu[64][264];
    const int tid = threadIdx.x;
    const int m0 = blockIdx.x * 64;
    const int wid = tid >> 6, lane = tid & 63;
    const int lr = lane & 15, lk = (lane >> 4) * 8;
    const int n0 = wid * 64;
    stage_x(x, m0, tid, xl);
    __syncthreads();
    // GEMM1: inline bf16 B-frag loads (L2-hot, 16B each), acc in AGPR
    f32x4 acc[4][4];
    #pragma unroll
    for (int i = 0; i < 4; ++i)
        #pragma unroll
        for (int j = 0; j < 4; ++j) acc[i][j] = f32x4{0.f, 0.f, 0.f, 0.f};
    #pragma unroll
    for (int ks = 0; ks < 4; ++ks) {
        int k = ks * 32 + lk;
        bf16x8 a[4], b[4];
        #pragma unroll
        for (int mf = 0; mf < 4; ++mf)
            a[mf] = *reinterpret_cast<const bf16x8*>(&xl[mf * 16 + lr][k]);
        #pragma unroll
        for (int nf = 0; nf < 4; ++nf)
            b[nf] = *reinterpret_cast<const bf16x8*>(&Bbf[(size_t)(n0 + nf * 16 + lr) * HIDDEN + k]);
        #pragma unroll
        for (int mf = 0; mf < 4; ++mf)
            #pragma unroll
            for (int nf = 0; nf < 4; ++nf)
                acc[mf][nf] = __builtin_amdgcn_mfma_f32_16x16x32_bf16(a[mf], b[nf], acc[mf][nf], 0, 0, 0);
    }
    const int mrow = (lane >> 4) * 4;
    #pragma unroll
    for (int mf = 0; mf < 4; ++mf)
        #pragma unroll
        for (int nf = 0; nf < 4; ++nf)
            #pragma unroll
            for (int r = 0; r < 4; ++r)
                bu[mf * 16 + mrow + r][n0 + nf * 16 + lr] = (bf16)acc[mf][nf][r];
    __syncthreads();
    // coalesced Bu store to HBM (issues early; drains under the scan)
    #pragma unroll
    for (int p = 0; p < 8; ++p) {
        int flat = p * 256 + tid;          // 64 rows x 32 chunks of 8 bf16
        int row = flat >> 5;
        int c8  = flat & 31;
        bf16x8 v = *reinterpret_cast<const bf16x8*>(&bu[row][c8 * 8]);
        *reinterpret_cast<bf16x8*>(&Bu_g[((size_t)(m0 + row)) * STATE + c8 * 8]) = v;
    }
    // local scan (phase A), thread = state n
    const int n = tid;
    float m11, m12, m21, m22, c1, c2;
    scan_params(A_diag, steps, n, m11, m12, m21, m22, c1, c2);
    float s1 = 0.f, s2 = 0.f;
    #pragma unroll 8
    for (int t = 0; t < LCHUNK; ++t) {
        float v = (float)bu[t][n];
        float ns1 = fmaf(m11, s1, fmaf(m12, s2, c1 * v));
        float ns2 = fmaf(m21, s1, fmaf(m22, s2, c2 * v));
        s1 = ns1; s2 = ns2;
    }
    const int b = m0 >> 12;            // /SEQ
    const int chunk = (m0 >> 6) & (NCHUNK - 1);
    size_t base = ((size_t)(b * NCHUNK + chunk) * 2) * STATE + n;
    cs[base] = s1;
    cs[base + STATE] = s2;
}

// ---------------- phase B: cross-chunk combine (M^64 via squaring) ----------------
__global__ __launch_bounds__(256) void scan_comb(float* __restrict__ cs,
        const float* __restrict__ A_diag, const float* __restrict__ steps) {
    const int n = threadIdx.x;
    const int b = blockIdx.x;
    float p11, p12, p21, p22, c1u, c2u;
    scan_params(A_diag, steps, n, p11, p12, p21, p22, c1u, c2u);
    #pragma unroll
    for (int i = 0; i < 6; ++i) {   // M^(2^6) = M^64
        float q11 = p11 * p11 + p12 * p21;
        float q12 = p11 * p12 + p12 * p22;
        float q21 = p21 * p11 + p22 * p21;
        float q22 = p21 * p12 + p22 * p22;
        p11 = q11; p12 = q12; p21 = q21; p22 = q22;
    }
    float S1 = 0.f, S2 = 0.f;
    #pragma unroll 8
    for (int c = 0; c < NCHUNK; ++c) {
        size_t base = ((size_t)(b * NCHUNK + c) * 2) * STATE + n;
        float q1 = cs[base], q2 = cs[base + STATE];
        cs[base] = S1; cs[base + STATE] = S2;
        float n1 = fmaf(p11, S1, fmaf(p12, S2, q1));
        float n2 = fmaf(p21, S1, fmaf(p22, S2, q2));
        S1 = n1; S2 = n2;
    }
}

// ---------------- K2': stage Bu + phase-C scan + GEMM2 + D*x ----------------
// LDS = bu only (34 KB) -> 4 blocks/CU; 3 short phases.
__global__ __launch_bounds__(256, 3) void k2_scan_gemm(const bf16* __restrict__ Bu_g,
        const bf16* __restrict__ Cbf, const float* __restrict__ x,
        const float* __restrict__ A_diag, const float* __restrict__ steps,
        const float* __restrict__ cs, const float* __restrict__ Dv,
        float* __restrict__ out) {
    __shared__ bf16 bu[64][264];            // reused as fp32 [64][132] for epilogue
    float (*ldsF)[132] = reinterpret_cast<float(*)[132]>(&bu[0][0]);
    const int tid = threadIdx.x;
    const int m0 = blockIdx.x * 64;
    const int wid = tid >> 6, lane = tid & 63;
    const int lr = lane & 15, lk = (lane >> 4) * 8;
    const int h0 = wid * 32;
    // stage Bu tile (coalesced 16B loads -> LDS)
    #pragma unroll
    for (int p = 0; p < 8; ++p) {
        int flat = p * 256 + tid;
        int row = flat >> 5;
        int c8  = flat & 31;
        bf16x8 v = *reinterpret_cast<const bf16x8*>(&Bu_g[((size_t)(m0 + row)) * STATE + c8 * 8]);
        *reinterpret_cast<bf16x8*>(&bu[row][c8 * 8]) = v;
    }
    // T14: issue x loads for the epilogue now; consumed after GEMM2
    float4 xreg[8];
    #pragma unroll
    for (int p = 0; p < 8; ++p) {
        int flat = p * 256 + tid;
        int row = flat >> 5;
        int c4  = flat & 31;
        xreg[p] = *reinterpret_cast<const float4*>(&x[(size_t)(m0 + row) * HIDDEN + c4 * 4]);
    }
    // scan params + init state (hides under the Bu-stage vmcnt wait)
    const int n = tid;
    float m11, m12, m21, m22, c1, c2;
    scan_params(A_diag, steps, n, m11, m12, m21, m22, c1, c2);
    const int b = m0 >> 12;
    const int chunk = (m0 >> 6) & (NCHUNK - 1);
    size_t cbase = ((size_t)(b * NCHUNK + chunk) * 2) * STATE + n;
    float s1 = cs[cbase], s2 = cs[cbase + STATE];
    __syncthreads();
    // phase-C scan; overwrite bu with y = s2 (bf16)
    #pragma unroll 8
    for (int t = 0; t < LCHUNK; ++t) {
        float v = (float)bu[t][n];
        float ns1 = fmaf(m11, s1, fmaf(m12, s2, c1 * v));
        float ns2 = fmaf(m21, s1, fmaf(m22, s2, c2 * v));
        s1 = ns1; s2 = ns2;
        bu[t][n] = (bf16)s2;
    }
    __syncthreads();
    // GEMM2: y @ C^T, inline bf16 C-frag loads (L2-hot)
    f32x4 acc2[4][2];
    #pragma unroll
    for (int i = 0; i < 4; ++i) {
        acc2[i][0] = f32x4{0.f, 0.f, 0.f, 0.f};
        acc2[i][1] = f32x4{0.f, 0.f, 0.f, 0.f};
    }
    #pragma unroll
    for (int ks = 0; ks < 8; ++ks) {
        int k = ks * 32 + lk;
        bf16x8 a[4], bb[2];
        #pragma unroll
        for (int mf = 0; mf < 4; ++mf)
            a[mf] = *reinterpret_cast<const bf16x8*>(&bu[mf * 16 + lr][k]);
        #pragma unroll
        for (int hf = 0; hf < 2; ++hf)
            bb[hf] = *reinterpret_cast<const bf16x8*>(&Cbf[(size_t)(h0 + hf * 16 + lr) * STATE + k]);
        #pragma unroll
        for (int mf = 0; mf < 4; ++mf)
            #pragma unroll
            for (int hf = 0; hf < 2; ++hf)
                acc2[mf][hf] = __builtin_amdgcn_mfma_f32_16x16x32_bf16(a[mf], bb[hf], acc2[mf][hf], 0, 0, 0);
    }
    __syncthreads();   // all bu reads done before fp32 reuse
    // stage acc2 -> ldsF[t][h]
    const int mrow = (lane >> 4) * 4;
    #pragma unroll
    for (int mf = 0; mf < 4; ++mf)
        #pragma unroll
        for (int hf = 0; hf < 2; ++hf)
            #pragma unroll
            for (int r = 0; r < 4; ++r)
                ldsF[mf * 16 + mrow + r][h0 + hf * 16 + lr] = acc2[mf][hf][r];
    __syncthreads();
    // coalesced epilogue: out = ldsF + D*x (x exact fp32 from xreg)
    #pragma unroll
    for (int p = 0; p < 8; ++p) {
        int flat = p * 256 + tid;
        int row = flat >> 5;
        int c4  = flat & 31;
        float4 f = *reinterpret_cast<const float4*>(&ldsF[row][c4 * 4]);
        float4 d = *reinterpret_cast<const float4*>(&Dv[c4 * 4]);
        float4 o;
        o.x = f.x + d.x * xreg[p].x;
        o.y = f.y + d.y * xreg[p].y;
        o.z = f.z + d.z * xreg[p].z;
        o.w = f.w + d.w * xreg[p].w;
        *reinterpret_cast<float4*>(&out[(size_t)(m0 + row) * HIDDEN + c4 * 4]) = o;
    }
}

extern "C" void kernel_launch(void* const* d_in, const int* in_sizes, int n_in,
                              void* d_out, int out_size, void* d_ws, size_t ws_size,
                              hipStream_t stream) {
    const float* x      = (const float*)d_in[0];
    const float* A_diag = (const float*)d_in[1];
    const float* steps  = (const float*)d_in[2];
    const float* Bm     = (const float*)d_in[3];
    const float* Cm     = (const float*)d_in[4];
    const float* Dv     = (const float*)d_in[5];
    float* out = (float*)d_out;

    char* ws = (char*)d_ws;
    const size_t CS_BYTES = (size_t)BATCHN * NCHUNK * 2 * STATE * 4;  // 2 MB
    float* cs  = (float*)ws;
    bf16*  Bbf = (bf16*)(ws + CS_BYTES);
    bf16*  Cbf = (bf16*)(ws + CS_BYTES + (size_t)STATE * HIDDEN * 2);
    bf16*  Bu_g = (bf16*)(ws + CS_BYTES + (size_t)STATE * HIDDEN * 4);  // 32 MB

    hipLaunchKernelGGL(setup_k, dim3(128), dim3(256), 0, stream, Bm, Cm, Bbf, Cbf);
    hipLaunchKernelGGL(k1_gemm_scanA, dim3(MTOT / 64), dim3(256), 0, stream,
                       x, Bbf, A_diag, steps, cs, Bu_g);
    hipLaunchKernelGGL(scan_comb, dim3(BATCHN), dim3(256), 0, stream, cs, A_diag, steps);
    hipLaunchKernelGGL(k2_scan_gemm, dim3(MTOT / 64), dim3(256), 0, stream,
                       Bu_g, Cbf, x, A_diag, steps, cs, Dv, out);
}